// Round 5
// baseline (362.897 us; speedup 1.0000x reference)
//
#include <hip/hip_runtime.h>

typedef unsigned short u16;
typedef __attribute__((ext_vector_type(8))) short short8;
typedef __attribute__((ext_vector_type(4))) float floatx4;

#define MFMA16(A, B, C) __builtin_amdgcn_mfma_f32_16x16x32_bf16((A), (B), (C), 0, 0, 0)

// ws layout (u16 element offsets)
#define OF_PART  64                        // 8x256 f32 partials for fused bp (4096 u16)
#define OF_FQKV  (OF_PART + 4096)          // fq,fk,fv f32 (3x256 -> 1536 u16)
#define OF_SORT  (OF_FQKV + 1536)          // 256 f32 thresholds (512 u16)
#define OF_TAB   (OF_SORT + 512)           // 6 tables bf16 [257][256]: Aq Bq Ak Bk Av Bv
#define OF_WP    (OF_TAB + 6 * 65792)      // Wp' bf16 frag-major (524288 u16)
#define OF_ORAW  (OF_WP + 524288)          // o_raw bf16 frag-major [256 kb8][25600 m][8]
#define OF_WQB   OF_ORAW                   // overlay: Wq'/Wk'/Wv' bf16 row-major (3x65536),
                                           // dead before fused writes o_raw
#define NPM8     204800                    // 25600 patches * 8

static __device__ __forceinline__ float bf2f(u16 u) {
  union { unsigned int i; float f; } z; z.i = ((unsigned int)u) << 16; return z.f;
}
static __device__ __forceinline__ u16 f2bf(float f) {
  union { float f; unsigned int i; } z; z.f = f;
  unsigned int x = z.i + 0x7fffu + ((z.i >> 16) & 1u);  // RNE
  return (u16)(x >> 16);
}
static __device__ __forceinline__ void ld8f(const u16* p, float* o) {
  union { short8 v; u16 u[8]; } t;
  t.v = *(const short8*)p;
#pragma unroll
  for (int j = 0; j < 8; ++j) o[j] = bf2f(t.u[j]);
}

// bf16 (0) vs f32 (1) input detection on first 256 u16 of spec; per-wave ballot.
static __device__ __forceinline__ int detect_flag(const u16* __restrict__ sp) {
  const int lane = threadIdx.x & 63;
  int bad = 0;
#pragma unroll
  for (int j = 0; j < 4; ++j) {
    u16 v = sp[lane * 4 + j];
    int e = (v >> 7) & 0xFF;
    bad += (e >= 137);
  }
  return (__popcll(__ballot(bad > 0)) >= 4) ? 1 : 0;
}

#define CV(src, idx) (flag ? f2bf(((const float*)(src))[idx]) : ((const u16*)(src))[idx])

// prep1: blocks 0..175: 11 fold GEMMs of 256x256x256 (16 sub-blocks of 64x64):
//   g=0..2:  Wg' = W2 @ {Wq,Wk,Wv} -> bf16 row-major [k][n] at OF_WQB
//   g=3..10: Wp'_p = Wo @ Wp[p*256:...] -> bf16 frag-major at OF_WP
// blocks 176..186: fq/fk/fv (f32) + 8 f32 partials for fused bp.
__global__ void prep1_kernel(
    const void* spec, const void* W2,
    const void* Wq, const void* bq, const void* Wk, const void* bk, const void* Wv,
    const void* bv_, const void* Wo, const void* bo, const void* Wp, const void* b2,
    u16* __restrict__ ws) {
  const int flag = detect_flag((const u16*)spec);
  const int b = blockIdx.x, tid = threadIdx.x;
  if (b >= 176) {
    const int t = b - 176, n = tid;
    if (t < 3) {
      const void* SB = (t == 0) ? Wq : (t == 1) ? Wk : Wv;
      const void* bs = (t == 0) ? bq : (t == 1) ? bk : bv_;
      float acc;
      if (flag) {
        acc = ((const float*)bs)[n];
        const float* Bf = (const float*)SB; const float* b2f = (const float*)b2;
        for (int k = 0; k < 256; ++k) acc = fmaf(b2f[k], Bf[k * 256 + n], acc);
      } else {
        acc = bf2f(((const u16*)bs)[n]);
        const u16* Bh = (const u16*)SB; const u16* b2h = (const u16*)b2;
        for (int k = 0; k < 256; ++k) acc = fmaf(bf2f(b2h[k]), bf2f(Bh[k * 256 + n]), acc);
      }
      ((float*)(ws + OF_FQKV))[t * 256 + n] = acc;
    } else {
      const int p = t - 3;
      float acc = 0.f;
      if (flag) {
        const float* Wf = (const float*)Wp; const float* bf = (const float*)bo;
        for (int m = 0; m < 256; ++m) acc = fmaf(bf[m], Wf[(p * 256 + m) * 256 + n], acc);
      } else {
        const u16* Wh = (const u16*)Wp; const u16* bh = (const u16*)bo;
        for (int m = 0; m < 256; ++m)
          acc = fmaf(bf2f(bh[m]), bf2f(Wh[(p * 256 + m) * 256 + n]), acc);
      }
      ((float*)(ws + OF_PART))[p * 256 + n] = acc;
    }
    return;
  }
  const int g = b >> 4, sub = b & 15;
  const int r0 = (sub >> 2) * 64, c0 = (sub & 3) * 64;
  const void* SA = (g < 3) ? W2 : Wo;
  const void* SB = (g == 0) ? Wq : (g == 1) ? Wk : (g == 2) ? Wv : Wp;
  const int brow0 = (g < 3) ? 0 : (g - 3) * 256;
  const int w = tid >> 6, lane = tid & 63, l15 = lane & 15, quad = lane >> 4;
  const int arow = r0 + w * 16 + l15;
  floatx4 acc[4];
#pragma unroll
  for (int ni = 0; ni < 4; ++ni) acc[ni] = (floatx4){0.f, 0.f, 0.f, 0.f};
  if (flag) {
    const float* A = (const float*)SA; const float* B = (const float*)SB;
    for (int kc = 0; kc < 8; ++kc) {
      const int k0 = kc * 32 + quad * 8;
      floatx4 a0 = *(const floatx4*)(A + arow * 256 + k0);
      floatx4 a1 = *(const floatx4*)(A + arow * 256 + k0 + 4);
      union { short8 s8; u16 u[8]; } av;
#pragma unroll
      for (int j = 0; j < 4; ++j) { av.u[j] = f2bf(a0[j]); av.u[4 + j] = f2bf(a1[j]); }
#pragma unroll
      for (int ni = 0; ni < 4; ++ni) {
        const int colx = c0 + ni * 16 + l15;
        union { short8 s8; u16 u[8]; } bu;
#pragma unroll
        for (int j = 0; j < 8; ++j) bu.u[j] = f2bf(B[(brow0 + k0 + j) * 256 + colx]);
        acc[ni] = MFMA16(av.s8, bu.s8, acc[ni]);
      }
    }
  } else {
    const u16* A = (const u16*)SA; const u16* B = (const u16*)SB;
    for (int kc = 0; kc < 8; ++kc) {
      const int k0 = kc * 32 + quad * 8;
      short8 av = *(const short8*)(A + arow * 256 + k0);
#pragma unroll
      for (int ni = 0; ni < 4; ++ni) {
        const int colx = c0 + ni * 16 + l15;
        union { short8 s8; u16 u[8]; } bu;
#pragma unroll
        for (int j = 0; j < 8; ++j) bu.u[j] = B[(brow0 + k0 + j) * 256 + colx];
        acc[ni] = MFMA16(av, bu.s8, acc[ni]);
      }
    }
  }
  if (g < 3) {
    u16* dst = ws + OF_WQB + g * 65536;
#pragma unroll
    for (int ni = 0; ni < 4; ++ni) {
      const int n = c0 + ni * 16 + l15;
#pragma unroll
      for (int r = 0; r < 4; ++r) {
        const int k = r0 + w * 16 + quad * 4 + r;
        dst[k * 256 + n] = f2bf(acc[ni][r]);
      }
    }
  } else {
    u16* dst = ws + OF_WP;
#pragma unroll
    for (int ni = 0; ni < 4; ++ni) {
      const int n = c0 + ni * 16 + l15;
#pragma unroll
      for (int r = 0; r < 4; ++r) {
        const int k = brow0 + r0 + w * 16 + quad * 4 + r;
        dst[(k >> 3) * 2048 + n * 8 + (k & 7)] = f2bf(acc[ni][r]);
      }
    }
  }
}

// prep2: 48 blocks = 6 tables x 8 r-segments. Each block: load W1/b1, compute
// thresholds t_k = -b1_k/W1_k (INF if W1_k==0), bitonic-sort (t,k) in LDS, then
// prefix-walk the rank-1 events writing its segment of the 257x256 bf16 table.
//   A_x[r][n] = sum_{k active at level r} W1_k * Wx'[k][n]
//   B_x[r][n] = sum_{k active at level r} b1_k * Wx'[k][n] + fx[n]
// level r = #events with t < s; event k: W1>0 activates, W1<0 deactivates.
__global__ void prep2_kernel(const void* spec, const void* W1, const void* b1,
                             u16* __restrict__ ws) {
  const int flag = detect_flag((const u16*)spec);
  const int tid = threadIdx.x;
  const int tbl = blockIdx.x >> 3, seg = blockIdx.x & 7;
  __shared__ float st[256];
  __shared__ int   sk[256];
  __shared__ float w1f[256], b1f[256];
  w1f[tid] = flag ? ((const float*)W1)[tid] : bf2f(((const u16*)W1)[tid]);
  b1f[tid] = flag ? ((const float*)b1)[tid] : bf2f(((const u16*)b1)[tid]);
  __syncthreads();
  {
    const float w = w1f[tid];
    st[tid] = (w != 0.f) ? (-b1f[tid] / w) : 1e30f;
    sk[tid] = tid;
  }
  // bitonic sort ascending by t
  for (int size = 2; size <= 256; size <<= 1) {
    for (int stride = size >> 1; stride > 0; stride >>= 1) {
      __syncthreads();
      const int ixj = tid ^ stride;
      if (ixj > tid) {
        const bool up = ((tid & size) == 0);
        float a = st[tid], bq = st[ixj];
        if (up ? (a > bq) : (a < bq)) {
          int ka = sk[tid];
          st[tid] = bq; st[ixj] = a;
          sk[tid] = sk[ixj]; sk[ixj] = ka;
        }
      }
    }
  }
  __syncthreads();
  if (blockIdx.x == 0) ((float*)(ws + OF_SORT))[tid] = st[tid];

  const int m = tbl >> 1, isB = tbl & 1;
  const u16* S = ws + OF_WQB + m * 65536;
  float cur = isB ? ((const float*)(ws + OF_FQKV))[m * 256 + tid] : 0.f;
  // base: active at s = -inf
  for (int k = 0; k < 256; ++k) {
    const float w = w1f[k], bb = b1f[k];
    const bool act = (w < 0.f) || (w == 0.f && bb > 0.f);
    if (act) cur = fmaf(isB ? bb : w, bf2f(S[k * 256 + tid]), cur);
  }
  const int rlo = seg * 32;
  const int rhi = seg * 32 + 31 + (seg == 7 ? 1 : 0);
  u16* dst = ws + OF_TAB + tbl * 65792;
  if (rlo == 0) dst[tid] = f2bf(cur);
  for (int e = 0; e < 256; ++e) {
    const int ke = sk[e];
    const float w = w1f[ke];
    const float sg = (w > 0.f) ? 1.f : ((w < 0.f) ? -1.f : 0.f);
    cur = fmaf(sg * (isB ? b1f[ke] : w), bf2f(S[ke * 256 + tid]), cur);
    const int L = e + 1;
    if (L >= rlo && L <= rhi) dst[L * 256 + tid] = f2bf(cur);
    if (L > rhi) break;
  }
}

// One block = 64 tokens = 8 windows. q/k/v come from the threshold-rank tables:
// q = s*Aq[r] + Bq[r] built directly into MFMA fragments (no QKV GEMM, no a-tile).
// Attention on matrix pipe (as round 4); raw o written frag-major to o_raw.
__global__ __launch_bounds__(256) void fused_lite_kernel(
    const void* __restrict__ spec, const float* __restrict__ tsort,
    const u16* __restrict__ tAq, const u16* __restrict__ tBq,
    const u16* __restrict__ tAk, const u16* __restrict__ tBk,
    const u16* __restrict__ tAv, const u16* __restrict__ tBv,
    u16* __restrict__ oraw)
{
  __shared__ u16 vbT[16384];          // 64 tok x 256 dims transposed, swizzled (32 KB)
  __shared__ u16 pscr[1024];          // per-wave P scratch (head-at-a-time)
  __shared__ float sS[64];
  __shared__ int   sR[64];
  __shared__ int   part[256];

  const int flag = detect_flag((const u16*)spec);
  const int tid = threadIdx.x;
  const int wave = tid >> 6, lane = tid & 63;
  const int l15 = lane & 15, quad = lane >> 4;
  const int tile0 = blockIdx.x * 64;
  const floatx4 zero4 = (floatx4){0.f, 0.f, 0.f, 0.f};

  // phase 0: per-token s and rank r = #{t < s} (4 threads/token count 64 each)
  {
    const int m = tid & 63, qt = tid >> 6;
    const float sm = flag ? ((const float*)spec)[tile0 + m]
                          : bf2f(((const u16*)spec)[tile0 + m]);
    int cnt = 0;
#pragma unroll 8
    for (int j = 0; j < 64; ++j) cnt += (tsort[qt * 64 + j] < sm) ? 1 : 0;
    part[tid] = cnt;
    __syncthreads();
    if (tid < 64) {
      sR[tid] = part[tid] + part[tid + 64] + part[tid + 128] + part[tid + 192];
      sS[tid] = sm;
    }
    __syncthreads();
  }

  // phase 1: v-fill. wave w handles tokens w*16..w*16+15 (l15), dims quad*64..+64.
  {
    const int tok = wave * 16 + l15;
    const int r = sR[tok];
    const float s = sS[tok];
    const u16* Ar = tAv + r * 256;
    const u16* Br = tBv + r * 256;
#pragma unroll
    for (int j8 = 0; j8 < 8; ++j8) {
      const int d8 = quad * 64 + j8 * 8;
      float af[8], bf8[8];
      ld8f(Ar + d8, af);
      ld8f(Br + d8, bf8);
#pragma unroll
      for (int e = 0; e < 8; ++e) {
        const int d = d8 + e;
        vbT[d * 64 + (((tok >> 3) ^ (d & 7)) << 3) + (tok & 7)] =
            f2bf(fmaf(s, af[e], bf8[e]));
      }
    }
  }
  __syncthreads();

  // phase 2: attention, head-at-a-time. Wave w owns windows {2w, 2w+1}.
  unsigned opk[32];
  {
    const int w2 = wave * 2;
    const int tok = wave * 16 + l15;
    const int r_t = sR[tok];
    const float s_t = sS[tok];
    const int validk = ((l15 >> 3) == (quad >> 1));
    u16* ps = pscr + wave * 256;
#pragma unroll
    for (int h = 0; h < 8; ++h) {
      const int d8 = h * 32 + quad * 8;
      short8 qv, kv;
      {
        float a[8], b[8];
        ld8f(tAq + r_t * 256 + d8, a);
        ld8f(tBq + r_t * 256 + d8, b);
        union { short8 s8; u16 u[8]; } z;
#pragma unroll
        for (int e = 0; e < 8; ++e) z.u[e] = f2bf(fmaf(s_t, a[e], b[e]));
        qv = z.s8;
      }
      {
        float a[8], b[8];
        ld8f(tAk + r_t * 256 + d8, a);
        ld8f(tBk + r_t * 256 + d8, b);
        union { short8 s8; u16 u[8]; } z;
#pragma unroll
        for (int e = 0; e < 8; ++e) z.u[e] = f2bf(fmaf(s_t, a[e], b[e]));
        kv = z.s8;
      }
      floatx4 sc = MFMA16(qv, kv, zero4);
      u16 pb[4];
#pragma unroll
      for (int r = 0; r < 4; ++r) {
        float s = sc[r] * 0.17677669529663687f;   // 1/sqrt(32)
        float mx = fmaxf(s, __shfl_xor(s, 1));
        mx = fmaxf(mx, __shfl_xor(mx, 2));
        mx = fmaxf(mx, __shfl_xor(mx, 4));
        float p = __expf(s - mx);
        float sum = p + __shfl_xor(p, 1);
        sum += __shfl_xor(sum, 2);
        sum += __shfl_xor(sum, 4);
        pb[r] = f2bf(validk ? p / sum : 0.f);
      }
#pragma unroll
      for (int r = 0; r < 4; ++r) ps[(quad * 4 + r) * 16 + l15] = pb[r];
#pragma unroll
      for (int dh = 0; dh < 2; ++dh) {
        const int vcol = h * 32 + dh * 16 + l15;
        short8 pa = (short8){0, 0, 0, 0, 0, 0, 0, 0};
        short8 vf = (short8){0, 0, 0, 0, 0, 0, 0, 0};
        if (quad < 2) {
          pa = *(const short8*)(ps + l15 * 16 + quad * 8);
          vf = *(const short8*)(vbT + vcol * 64 + (((w2 + quad) ^ (vcol & 7)) << 3));
        }
        floatx4 o = MFMA16(pa, vf, zero4);
        opk[(h * 2 + dh) * 2]     = (unsigned)f2bf(o[0]) | ((unsigned)f2bf(o[1]) << 16);
        opk[(h * 2 + dh) * 2 + 1] = (unsigned)f2bf(o[2]) | ((unsigned)f2bf(o[3]) << 16);
      }
    }
  }

  // phase 3: opk -> o_raw (global, fragment-major).
  // token row = quad*4+r -> win = 2*wave + (quad>>1), p = (quad&1)*4 + r;
  // D = h*32 + dh*16 + l15 -> e8 = h*4 + dh*2 + (l15>>3).
  {
    const int mbase = (blockIdx.x * 8 + wave * 2 + (quad >> 1)) * 8 + (l15 & 7);
    const int pb4 = (quad & 1) * 4;
#pragma unroll
    for (int h = 0; h < 8; ++h)
#pragma unroll
      for (int dh = 0; dh < 2; ++dh) {
        const int oi = (h * 2 + dh) * 2;
        const int e8 = h * 4 + dh * 2 + (l15 >> 3);
        const unsigned lo = opk[oi], hi = opk[oi + 1];
        oraw[((pb4 + 0) * 32 + e8) * NPM8 + mbase] = (u16)lo;
        oraw[((pb4 + 1) * 32 + e8) * NPM8 + mbase] = (u16)(lo >> 16);
        oraw[((pb4 + 2) * 32 + e8) * NPM8 + mbase] = (u16)hi;
        oraw[((pb4 + 3) * 32 + e8) * NPM8 + mbase] = (u16)(hi >> 16);
      }
  }
}

// Patch projection GEMM: [25600 x 2048] @ Wp' [2048 x 256] + fb.
// M-tile 64, N-tile 128, 4 waves each 64x32; A and B direct from global
// (both fragment-major, coalesced b128); no LDS.
__global__ __launch_bounds__(256) void patch_gemm_kernel(
    const u16* __restrict__ spec_raw,
    const u16* __restrict__ oraw, const u16* __restrict__ sWp,
    const void* __restrict__ bp, const float* __restrict__ part,
    void* __restrict__ out)
{
  const int flag = detect_flag(spec_raw);
  const int tid = threadIdx.x;
  const int wave = tid >> 6, lane = tid & 63;
  const int l15 = lane & 15, quad = lane >> 4;
  const int m0 = (blockIdx.x >> 1) * 64;
  const int n0 = (blockIdx.x & 1) * 128 + wave * 32;
  const floatx4 zero4 = (floatx4){0.f, 0.f, 0.f, 0.f};

  floatx4 acc[4][2];
#pragma unroll
  for (int mi = 0; mi < 4; ++mi)
#pragma unroll
    for (int ni = 0; ni < 2; ++ni) acc[mi][ni] = zero4;

  const u16* ap = oraw + quad * NPM8 + (m0 + l15) * 8;
  const u16* bpw = sWp + quad * 2048 + (n0 + l15) * 8;
#pragma unroll 4
  for (int kk = 0; kk < 64; ++kk) {
    short8 b0 = *(const short8*)(bpw);
    short8 b1 = *(const short8*)(bpw + 128);         // +16 cols
#pragma unroll
    for (int mi = 0; mi < 4; ++mi) {
      short8 a = *(const short8*)(ap + mi * 128);    // +16 rows per mi
      acc[mi][0] = MFMA16(a, b0, acc[mi][0]);
      acc[mi][1] = MFMA16(a, b1, acc[mi][1]);
    }
    ap += 4 * NPM8;
    bpw += 4 * 2048;
  }

  // epilogue: fb = bp + sum of the 8 bo@Wp_p partials (f32)
#pragma unroll
  for (int ni = 0; ni < 2; ++ni) {
    const int n = n0 + ni * 16 + l15;
    float bb = bf2f(CV(bp, n));
#pragma unroll
    for (int p = 0; p < 8; ++p) bb += part[p * 256 + n];
#pragma unroll
    for (int mi = 0; mi < 4; ++mi) {
      const int mr = m0 + mi * 16 + quad * 4;
      if (flag) {
        float* po = (float*)out;
#pragma unroll
        for (int r = 0; r < 4; ++r)
          po[(mr + r) * 256 + n] = acc[mi][ni][r] + bb;
      } else {
        u16* po = (u16*)out;
#pragma unroll
        for (int r = 0; r < 4; ++r)
          po[(mr + r) * 256 + n] = f2bf(acc[mi][ni][r] + bb);
      }
    }
  }
}

extern "C" void kernel_launch(void* const* d_in, const int* in_sizes, int n_in,
                              void* d_out, int out_size, void* d_ws, size_t ws_size,
                              hipStream_t stream) {
  (void)in_sizes; (void)n_in; (void)out_size; (void)ws_size;
  u16* ws = (u16*)d_ws;

  prep1_kernel<<<187, 256, 0, stream>>>(
      d_in[0], d_in[3],
      d_in[5], d_in[6], d_in[7], d_in[8], d_in[9], d_in[10],
      d_in[11], d_in[12], d_in[13], d_in[4], ws);
  prep2_kernel<<<48, 256, 0, stream>>>(d_in[0], d_in[1], d_in[2], ws);
  fused_lite_kernel<<<3200, 256, 0, stream>>>(
      d_in[0], (const float*)(ws + OF_SORT),
      ws + OF_TAB,              ws + OF_TAB + 65792,
      ws + OF_TAB + 2 * 65792,  ws + OF_TAB + 3 * 65792,
      ws + OF_TAB + 4 * 65792,  ws + OF_TAB + 5 * 65792,
      ws + OF_ORAW);
  patch_gemm_kernel<<<800, 256, 0, stream>>>(
      (const u16*)d_in[0],
      ws + OF_ORAW, ws + OF_WP,
      d_in[14], (const float*)(ws + OF_PART),
      d_out);
}

// Round 6
// 258.668 us; speedup vs baseline: 1.4029x; 1.4029x over previous
//
#include <hip/hip_runtime.h>

typedef unsigned short u16;
typedef __attribute__((ext_vector_type(8))) short short8;
typedef __attribute__((ext_vector_type(4))) float floatx4;

#define MFMA16(A, B, C) __builtin_amdgcn_mfma_f32_16x16x32_bf16((A), (B), (C), 0, 0, 0)

// ws layout (u16 element offsets)
#define OF_PART  64                        // 8x256 f32 partials for fused bp (4096 u16)
#define OF_FQKV  (OF_PART + 4096)          // fq,fk,fv f32 (3x256 -> 1536 u16)
#define OF_SORT  (OF_FQKV + 1536)          // 256 f32 sorted thresholds (512 u16)
#define OF_EVK   (OF_SORT + 512)           // 256 u16 sorted event k-indices
#define OF_CA    (OF_EVK + 256)            // 256 f32 event coefs for A tables (sg*w1)
#define OF_CB    (OF_CA + 512)             // 256 f32 event coefs for B tables (sg*b1)
#define OF_MA    (OF_CB + 512)             // 256 f32 base coefs A (act0 ? w1 : 0)
#define OF_MB    (OF_MA + 512)             // 256 f32 base coefs B (act0 ? b1 : 0)
#define OF_P2    (OF_MB + 512)             // scan partials f32 [6 tbl][8 chunk][2][256]
#define OF_TAB   (OF_P2 + 49152)           // 6 tables bf16 [257][256]: Aq Bq Ak Bk Av Bv
#define OF_WP    (OF_TAB + 6 * 65792)      // Wp' bf16 frag-major (524288 u16)
#define OF_ORAW  (OF_WP + 524288)          // o_raw bf16 frag-major [256 kb8][25600 m][8]
#define OF_WQB   OF_ORAW                   // overlay: Wq'/Wk'/Wv' bf16 row-major (3x65536),
                                           // dead before fused writes o_raw
#define NPM8     204800                    // 25600 patches * 8

static __device__ __forceinline__ float bf2f(u16 u) {
  union { unsigned int i; float f; } z; z.i = ((unsigned int)u) << 16; return z.f;
}
static __device__ __forceinline__ u16 f2bf(float f) {
  union { float f; unsigned int i; } z; z.f = f;
  unsigned int x = z.i + 0x7fffu + ((z.i >> 16) & 1u);  // RNE
  return (u16)(x >> 16);
}
static __device__ __forceinline__ void ld8f(const u16* p, float* o) {
  union { short8 v; u16 u[8]; } t;
  t.v = *(const short8*)p;
#pragma unroll
  for (int j = 0; j < 8; ++j) o[j] = bf2f(t.u[j]);
}

// bf16 (0) vs f32 (1) input detection on first 256 u16 of spec; per-wave ballot.
static __device__ __forceinline__ int detect_flag(const u16* __restrict__ sp) {
  const int lane = threadIdx.x & 63;
  int bad = 0;
#pragma unroll
  for (int j = 0; j < 4; ++j) {
    u16 v = sp[lane * 4 + j];
    int e = (v >> 7) & 0xFF;
    bad += (e >= 137);
  }
  return (__popcll(__ballot(bad > 0)) >= 4) ? 1 : 0;
}

#define CV(src, idx) (flag ? f2bf(((const float*)(src))[idx]) : ((const u16*)(src))[idx])

// prep1: blocks 0..175: 11 fold GEMMs of 256x256x256 (16 sub-blocks of 64x64):
//   g=0..2:  Wg' = W2 @ {Wq,Wk,Wv} -> bf16 row-major [k][n] at OF_WQB
//   g=3..10: Wp'_p = Wo @ Wp[p*256:...] -> bf16 frag-major at OF_WP
// blocks 176..186: fq/fk/fv (f32) + 8 f32 partials for fused bp.
// block  187: threshold sort + event/base coef tables (for the prefix scan).
__global__ void prep1_kernel(
    const void* spec, const void* W1, const void* b1, const void* W2,
    const void* Wq, const void* bq, const void* Wk, const void* bk, const void* Wv,
    const void* bv_, const void* Wo, const void* bo, const void* Wp, const void* b2,
    u16* __restrict__ ws) {
  const int flag = detect_flag((const u16*)spec);
  const int b = blockIdx.x, tid = threadIdx.x;
  if (b == 187) {
    // sort thresholds t_k = -b1_k/W1_k; emit event order + coefs.
    __shared__ float st[256];
    __shared__ int   sk[256];
    __shared__ float w1s[256], b1s[256];
    w1s[tid] = flag ? ((const float*)W1)[tid] : bf2f(((const u16*)W1)[tid]);
    b1s[tid] = flag ? ((const float*)b1)[tid] : bf2f(((const u16*)b1)[tid]);
    __syncthreads();
    {
      const float w = w1s[tid];
      st[tid] = (w != 0.f) ? (-b1s[tid] / w) : 1e30f;
      sk[tid] = tid;
    }
    for (int size = 2; size <= 256; size <<= 1) {
      for (int stride = size >> 1; stride > 0; stride >>= 1) {
        __syncthreads();
        const int ixj = tid ^ stride;
        if (ixj > tid) {
          const bool up = ((tid & size) == 0);
          float a = st[tid], bq2 = st[ixj];
          if (up ? (a > bq2) : (a < bq2)) {
            int ka = sk[tid];
            st[tid] = bq2; st[ixj] = a;
            sk[tid] = sk[ixj]; sk[ixj] = ka;
          }
        }
      }
    }
    __syncthreads();
    ((float*)(ws + OF_SORT))[tid] = st[tid];
    ws[OF_EVK + tid] = (u16)sk[tid];
    {
      const int ke = sk[tid];
      const float w = w1s[ke], bb = b1s[ke];
      const float sg = (w > 0.f) ? 1.f : ((w < 0.f) ? -1.f : 0.f);
      ((float*)(ws + OF_CA))[tid] = sg * w;
      ((float*)(ws + OF_CB))[tid] = sg * bb;
    }
    {
      const float wk = w1s[tid], bk2 = b1s[tid];
      const bool act0 = (wk < 0.f) || (wk == 0.f && bk2 > 0.f);
      ((float*)(ws + OF_MA))[tid] = act0 ? wk : 0.f;
      ((float*)(ws + OF_MB))[tid] = act0 ? bk2 : 0.f;
    }
    return;
  }
  if (b >= 176) {
    const int t = b - 176, n = tid;
    if (t < 3) {
      const void* SB = (t == 0) ? Wq : (t == 1) ? Wk : Wv;
      const void* bs = (t == 0) ? bq : (t == 1) ? bk : bv_;
      float acc;
      if (flag) {
        acc = ((const float*)bs)[n];
        const float* Bf = (const float*)SB; const float* b2f = (const float*)b2;
        for (int k = 0; k < 256; ++k) acc = fmaf(b2f[k], Bf[k * 256 + n], acc);
      } else {
        acc = bf2f(((const u16*)bs)[n]);
        const u16* Bh = (const u16*)SB; const u16* b2h = (const u16*)b2;
        for (int k = 0; k < 256; ++k) acc = fmaf(bf2f(b2h[k]), bf2f(Bh[k * 256 + n]), acc);
      }
      ((float*)(ws + OF_FQKV))[t * 256 + n] = acc;
    } else {
      const int p = t - 3;
      float acc = 0.f;
      if (flag) {
        const float* Wf = (const float*)Wp; const float* bf = (const float*)bo;
        for (int m = 0; m < 256; ++m) acc = fmaf(bf[m], Wf[(p * 256 + m) * 256 + n], acc);
      } else {
        const u16* Wh = (const u16*)Wp; const u16* bh = (const u16*)bo;
        for (int m = 0; m < 256; ++m)
          acc = fmaf(bf2f(bh[m]), bf2f(Wh[(p * 256 + m) * 256 + n]), acc);
      }
      ((float*)(ws + OF_PART))[p * 256 + n] = acc;
    }
    return;
  }
  const int g = b >> 4, sub = b & 15;
  const int r0 = (sub >> 2) * 64, c0 = (sub & 3) * 64;
  const void* SA = (g < 3) ? W2 : Wo;
  const void* SB = (g == 0) ? Wq : (g == 1) ? Wk : (g == 2) ? Wv : Wp;
  const int brow0 = (g < 3) ? 0 : (g - 3) * 256;
  const int w = tid >> 6, lane = tid & 63, l15 = lane & 15, quad = lane >> 4;
  const int arow = r0 + w * 16 + l15;
  floatx4 acc[4];
#pragma unroll
  for (int ni = 0; ni < 4; ++ni) acc[ni] = (floatx4){0.f, 0.f, 0.f, 0.f};
  if (flag) {
    const float* A = (const float*)SA; const float* B = (const float*)SB;
    for (int kc = 0; kc < 8; ++kc) {
      const int k0 = kc * 32 + quad * 8;
      floatx4 a0 = *(const floatx4*)(A + arow * 256 + k0);
      floatx4 a1 = *(const floatx4*)(A + arow * 256 + k0 + 4);
      union { short8 s8; u16 u[8]; } av;
#pragma unroll
      for (int j = 0; j < 4; ++j) { av.u[j] = f2bf(a0[j]); av.u[4 + j] = f2bf(a1[j]); }
#pragma unroll
      for (int ni = 0; ni < 4; ++ni) {
        const int colx = c0 + ni * 16 + l15;
        union { short8 s8; u16 u[8]; } bu;
#pragma unroll
        for (int j = 0; j < 8; ++j) bu.u[j] = f2bf(B[(brow0 + k0 + j) * 256 + colx]);
        acc[ni] = MFMA16(av.s8, bu.s8, acc[ni]);
      }
    }
  } else {
    const u16* A = (const u16*)SA; const u16* B = (const u16*)SB;
    for (int kc = 0; kc < 8; ++kc) {
      const int k0 = kc * 32 + quad * 8;
      short8 av = *(const short8*)(A + arow * 256 + k0);
#pragma unroll
      for (int ni = 0; ni < 4; ++ni) {
        const int colx = c0 + ni * 16 + l15;
        union { short8 s8; u16 u[8]; } bu;
#pragma unroll
        for (int j = 0; j < 8; ++j) bu.u[j] = B[(brow0 + k0 + j) * 256 + colx];
        acc[ni] = MFMA16(av, bu.s8, acc[ni]);
      }
    }
  }
  if (g < 3) {
    u16* dst = ws + OF_WQB + g * 65536;
#pragma unroll
    for (int ni = 0; ni < 4; ++ni) {
      const int n = c0 + ni * 16 + l15;
#pragma unroll
      for (int r = 0; r < 4; ++r) {
        const int k = r0 + w * 16 + quad * 4 + r;
        dst[k * 256 + n] = f2bf(acc[ni][r]);
      }
    }
  } else {
    u16* dst = ws + OF_WP;
#pragma unroll
    for (int ni = 0; ni < 4; ++ni) {
      const int n = c0 + ni * 16 + l15;
#pragma unroll
      for (int r = 0; r < 4; ++r) {
        const int k = brow0 + r0 + w * 16 + quad * 4 + r;
        dst[(k >> 3) * 2048 + n * 8 + (k & 7)] = f2bf(acc[ni][r]);
      }
    }
  }
}

// prep2a: scan partials. 48 blocks = 6 tables x 8 chunks; each block sums its
// 32 base terms and 32 event terms per column (independent coalesced loads).
__global__ void prep2a_kernel(u16* __restrict__ ws) {
  const int tbl = blockIdx.x >> 3, chunk = blockIdx.x & 7;
  const int n = threadIdx.x;
  const int m = tbl >> 1, isB = tbl & 1;
  const u16* S = ws + OF_WQB + m * 65536;
  const float* MC = (const float*)(ws + (isB ? OF_MB : OF_MA));
  const float* CC = (const float*)(ws + (isB ? OF_CB : OF_CA));
  const u16* EVK = ws + OF_EVK;
  float bacc = 0.f, eacc = 0.f;
#pragma unroll 8
  for (int j = 0; j < 32; ++j) {
    const int k = chunk * 32 + j;
    bacc = fmaf(MC[k], bf2f(S[k * 256 + n]), bacc);
    eacc = fmaf(CC[k], bf2f(S[EVK[k] * 256 + n]), eacc);
  }
  float* P = (float*)(ws + OF_P2);
  P[((tbl * 8 + chunk) * 2 + 0) * 256 + n] = bacc;
  P[((tbl * 8 + chunk) * 2 + 1) * 256 + n] = eacc;
}

// prep2b: 48 blocks = 6 tables x 8 segments. Seed cur from base partials +
// event-chunk prefix, then a 31/32-step local walk writing rows rlo..rlo+31
// (seg 7 also writes row 256).
//   A_x[r][n] = sum_{k active at level r} W1_k * Wx'[k][n]
//   B_x[r][n] = sum_{k active at level r} b1_k * Wx'[k][n] + fx[n]
__global__ void prep2b_kernel(u16* __restrict__ ws) {
  const int tbl = blockIdx.x >> 3, seg = blockIdx.x & 7;
  const int n = threadIdx.x;
  const int m = tbl >> 1, isB = tbl & 1;
  const u16* S = ws + OF_WQB + m * 65536;
  const float* CC = (const float*)(ws + (isB ? OF_CB : OF_CA));
  const u16* EVK = ws + OF_EVK;
  const float* P = (const float*)(ws + OF_P2);
  float cur = isB ? ((const float*)(ws + OF_FQKV))[m * 256 + n] : 0.f;
#pragma unroll
  for (int c = 0; c < 8; ++c) cur += P[((tbl * 8 + c) * 2 + 0) * 256 + n];
  for (int c = 0; c < seg; ++c) cur += P[((tbl * 8 + c) * 2 + 1) * 256 + n];
  u16* dst = ws + OF_TAB + tbl * 65792;
  const int rlo = seg * 32;
  dst[rlo * 256 + n] = f2bf(cur);
  const int nev = (seg == 7) ? 32 : 31;
  for (int i = 0; i < nev; ++i) {
    const int e = rlo + i;
    cur = fmaf(CC[e], bf2f(S[EVK[e] * 256 + n]), cur);
    dst[(e + 1) * 256 + n] = f2bf(cur);
  }
}

// One block = 64 tokens = 8 windows. q/k/v come from the threshold-rank tables:
// q = s*Aq[r] + Bq[r] built directly into MFMA fragments (no QKV GEMM, no a-tile).
// Attention on matrix pipe; raw o written frag-major to o_raw.
__global__ __launch_bounds__(256) void fused_lite_kernel(
    const void* __restrict__ spec, const float* __restrict__ tsort,
    const u16* __restrict__ tAq, const u16* __restrict__ tBq,
    const u16* __restrict__ tAk, const u16* __restrict__ tBk,
    const u16* __restrict__ tAv, const u16* __restrict__ tBv,
    u16* __restrict__ oraw)
{
  __shared__ u16 vbT[16384];          // 64 tok x 256 dims transposed, swizzled (32 KB)
  __shared__ u16 pscr[1024];          // per-wave P scratch (head-at-a-time)
  __shared__ float sS[64];
  __shared__ int   sR[64];
  __shared__ int   part[256];

  const int flag = detect_flag((const u16*)spec);
  const int tid = threadIdx.x;
  const int wave = tid >> 6, lane = tid & 63;
  const int l15 = lane & 15, quad = lane >> 4;
  const int tile0 = blockIdx.x * 64;
  const floatx4 zero4 = (floatx4){0.f, 0.f, 0.f, 0.f};

  // phase 0: per-token s and rank r = #{t < s} (4 threads/token count 64 each)
  {
    const int m = tid & 63, qt = tid >> 6;
    const float sm = flag ? ((const float*)spec)[tile0 + m]
                          : bf2f(((const u16*)spec)[tile0 + m]);
    int cnt = 0;
#pragma unroll 8
    for (int j = 0; j < 64; ++j) cnt += (tsort[qt * 64 + j] < sm) ? 1 : 0;
    part[tid] = cnt;
    __syncthreads();
    if (tid < 64) {
      sR[tid] = part[tid] + part[tid + 64] + part[tid + 128] + part[tid + 192];
      sS[tid] = sm;
    }
    __syncthreads();
  }

  // phase 1: v-fill. wave w handles tokens w*16..w*16+15 (l15), dims quad*64..+64.
  {
    const int tok = wave * 16 + l15;
    const int r = sR[tok];
    const float s = sS[tok];
    const u16* Ar = tAv + r * 256;
    const u16* Br = tBv + r * 256;
#pragma unroll
    for (int j8 = 0; j8 < 8; ++j8) {
      const int d8 = quad * 64 + j8 * 8;
      float af[8], bf8[8];
      ld8f(Ar + d8, af);
      ld8f(Br + d8, bf8);
#pragma unroll
      for (int e = 0; e < 8; ++e) {
        const int d = d8 + e;
        vbT[d * 64 + (((tok >> 3) ^ (d & 7)) << 3) + (tok & 7)] =
            f2bf(fmaf(s, af[e], bf8[e]));
      }
    }
  }
  __syncthreads();

  // phase 2: attention, head-at-a-time. Wave w owns windows {2w, 2w+1}.
  unsigned opk[32];
  {
    const int w2 = wave * 2;
    const int tok = wave * 16 + l15;
    const int r_t = sR[tok];
    const float s_t = sS[tok];
    const int validk = ((l15 >> 3) == (quad >> 1));
    u16* ps = pscr + wave * 256;
#pragma unroll
    for (int h = 0; h < 8; ++h) {
      const int d8 = h * 32 + quad * 8;
      short8 qv, kv;
      {
        float a[8], b[8];
        ld8f(tAq + r_t * 256 + d8, a);
        ld8f(tBq + r_t * 256 + d8, b);
        union { short8 s8; u16 u[8]; } z;
#pragma unroll
        for (int e = 0; e < 8; ++e) z.u[e] = f2bf(fmaf(s_t, a[e], b[e]));
        qv = z.s8;
      }
      {
        float a[8], b[8];
        ld8f(tAk + r_t * 256 + d8, a);
        ld8f(tBk + r_t * 256 + d8, b);
        union { short8 s8; u16 u[8]; } z;
#pragma unroll
        for (int e = 0; e < 8; ++e) z.u[e] = f2bf(fmaf(s_t, a[e], b[e]));
        kv = z.s8;
      }
      floatx4 sc = MFMA16(qv, kv, zero4);
      u16 pb[4];
#pragma unroll
      for (int r = 0; r < 4; ++r) {
        float s = sc[r] * 0.17677669529663687f;   // 1/sqrt(32)
        float mx = fmaxf(s, __shfl_xor(s, 1));
        mx = fmaxf(mx, __shfl_xor(mx, 2));
        mx = fmaxf(mx, __shfl_xor(mx, 4));
        float p = __expf(s - mx);
        float sum = p + __shfl_xor(p, 1);
        sum += __shfl_xor(sum, 2);
        sum += __shfl_xor(sum, 4);
        pb[r] = f2bf(validk ? p / sum : 0.f);
      }
#pragma unroll
      for (int r = 0; r < 4; ++r) ps[(quad * 4 + r) * 16 + l15] = pb[r];
#pragma unroll
      for (int dh = 0; dh < 2; ++dh) {
        const int vcol = h * 32 + dh * 16 + l15;
        short8 pa = (short8){0, 0, 0, 0, 0, 0, 0, 0};
        short8 vf = (short8){0, 0, 0, 0, 0, 0, 0, 0};
        if (quad < 2) {
          pa = *(const short8*)(ps + l15 * 16 + quad * 8);
          vf = *(const short8*)(vbT + vcol * 64 + (((w2 + quad) ^ (vcol & 7)) << 3));
        }
        floatx4 o = MFMA16(pa, vf, zero4);
        opk[(h * 2 + dh) * 2]     = (unsigned)f2bf(o[0]) | ((unsigned)f2bf(o[1]) << 16);
        opk[(h * 2 + dh) * 2 + 1] = (unsigned)f2bf(o[2]) | ((unsigned)f2bf(o[3]) << 16);
      }
    }
  }

  // phase 3: opk -> o_raw (global, fragment-major).
  {
    const int mbase = (blockIdx.x * 8 + wave * 2 + (quad >> 1)) * 8 + (l15 & 7);
    const int pb4 = (quad & 1) * 4;
#pragma unroll
    for (int h = 0; h < 8; ++h)
#pragma unroll
      for (int dh = 0; dh < 2; ++dh) {
        const int oi = (h * 2 + dh) * 2;
        const int e8 = h * 4 + dh * 2 + (l15 >> 3);
        const unsigned lo = opk[oi], hi = opk[oi + 1];
        oraw[((pb4 + 0) * 32 + e8) * NPM8 + mbase] = (u16)lo;
        oraw[((pb4 + 1) * 32 + e8) * NPM8 + mbase] = (u16)(lo >> 16);
        oraw[((pb4 + 2) * 32 + e8) * NPM8 + mbase] = (u16)hi;
        oraw[((pb4 + 3) * 32 + e8) * NPM8 + mbase] = (u16)(hi >> 16);
      }
  }
}

// Patch projection GEMM: [25600 x 2048] @ Wp' [2048 x 256] + fb.
// M-tile 64, N-tile 128, 4 waves each 64x32; A and B direct from global
// (both fragment-major, coalesced b128); no LDS.
__global__ __launch_bounds__(256) void patch_gemm_kernel(
    const u16* __restrict__ spec_raw,
    const u16* __restrict__ oraw, const u16* __restrict__ sWp,
    const void* __restrict__ bp, const float* __restrict__ part,
    void* __restrict__ out)
{
  const int flag = detect_flag(spec_raw);
  const int tid = threadIdx.x;
  const int wave = tid >> 6, lane = tid & 63;
  const int l15 = lane & 15, quad = lane >> 4;
  const int m0 = (blockIdx.x >> 1) * 64;
  const int n0 = (blockIdx.x & 1) * 128 + wave * 32;
  const floatx4 zero4 = (floatx4){0.f, 0.f, 0.f, 0.f};

  floatx4 acc[4][2];
#pragma unroll
  for (int mi = 0; mi < 4; ++mi)
#pragma unroll
    for (int ni = 0; ni < 2; ++ni) acc[mi][ni] = zero4;

  const u16* ap = oraw + quad * NPM8 + (m0 + l15) * 8;
  const u16* bpw = sWp + quad * 2048 + (n0 + l15) * 8;
#pragma unroll 4
  for (int kk = 0; kk < 64; ++kk) {
    short8 b0 = *(const short8*)(bpw);
    short8 b1 = *(const short8*)(bpw + 128);         // +16 cols
#pragma unroll
    for (int mi = 0; mi < 4; ++mi) {
      short8 a = *(const short8*)(ap + mi * 128);    // +16 rows per mi
      acc[mi][0] = MFMA16(a, b0, acc[mi][0]);
      acc[mi][1] = MFMA16(a, b1, acc[mi][1]);
    }
    ap += 4 * NPM8;
    bpw += 4 * 2048;
  }

  // epilogue: fb = bp + sum of the 8 bo@Wp_p partials (f32)
#pragma unroll
  for (int ni = 0; ni < 2; ++ni) {
    const int n = n0 + ni * 16 + l15;
    float bb = bf2f(CV(bp, n));
#pragma unroll
    for (int p = 0; p < 8; ++p) bb += part[p * 256 + n];
#pragma unroll
    for (int mi = 0; mi < 4; ++mi) {
      const int mr = m0 + mi * 16 + quad * 4;
      if (flag) {
        float* po = (float*)out;
#pragma unroll
        for (int r = 0; r < 4; ++r)
          po[(mr + r) * 256 + n] = acc[mi][ni][r] + bb;
      } else {
        u16* po = (u16*)out;
#pragma unroll
        for (int r = 0; r < 4; ++r)
          po[(mr + r) * 256 + n] = f2bf(acc[mi][ni][r] + bb);
      }
    }
  }
}

extern "C" void kernel_launch(void* const* d_in, const int* in_sizes, int n_in,
                              void* d_out, int out_size, void* d_ws, size_t ws_size,
                              hipStream_t stream) {
  (void)in_sizes; (void)n_in; (void)out_size; (void)ws_size;
  u16* ws = (u16*)d_ws;

  prep1_kernel<<<188, 256, 0, stream>>>(
      d_in[0], d_in[1], d_in[2], d_in[3],
      d_in[5], d_in[6], d_in[7], d_in[8], d_in[9], d_in[10],
      d_in[11], d_in[12], d_in[13], d_in[4], ws);
  prep2a_kernel<<<48, 256, 0, stream>>>(ws);
  prep2b_kernel<<<48, 256, 0, stream>>>(ws);
  fused_lite_kernel<<<3200, 256, 0, stream>>>(
      d_in[0], (const float*)(ws + OF_SORT),
      ws + OF_TAB,              ws + OF_TAB + 65792,
      ws + OF_TAB + 2 * 65792,  ws + OF_TAB + 3 * 65792,
      ws + OF_TAB + 4 * 65792,  ws + OF_TAB + 5 * 65792,
      ws + OF_ORAW);
  patch_gemm_kernel<<<800, 256, 0, stream>>>(
      (const u16*)d_in[0],
      ws + OF_ORAW, ws + OF_WP,
      d_in[14], (const float*)(ws + OF_PART),
      d_out);
}

// Round 7
// 254.099 us; speedup vs baseline: 1.4282x; 1.0180x over previous
//
#include <hip/hip_runtime.h>
#include <hip/hip_bf16.h>

typedef unsigned short u16;
typedef __attribute__((ext_vector_type(8))) short short8;
typedef __attribute__((ext_vector_type(4))) short short4_t;
typedef __attribute__((ext_vector_type(4))) float floatx4;

#define MFMA16(A, B, C) __builtin_amdgcn_mfma_f32_16x16x32_bf16((A), (B), (C), 0, 0, 0)

// ws layout (u16 element offsets)
#define OF_PART  64                        // 8x256 f32 partials for fused bp (4096 u16)
#define OF_FQKV  (OF_PART + 4096)          // fq,fk,fv f32 (3x256 -> 1536 u16)
#define OF_SORT  (OF_FQKV + 1536)          // 256 f32 sorted thresholds (512 u16)
#define OF_EVK   (OF_SORT + 512)           // 256 u16 sorted event k-indices
#define OF_CA    (OF_EVK + 256)            // 256 f32 event coefs for A tables (sg*w1)
#define OF_CB    (OF_CA + 512)             // 256 f32 event coefs for B tables (sg*b1)
#define OF_MA    (OF_CB + 512)             // 256 f32 base coefs A (act0 ? w1 : 0)
#define OF_MB    (OF_MA + 512)             // 256 f32 base coefs B (act0 ? b1 : 0)
#define OF_P2    (OF_MB + 512)             // scan partials f32 [6 tbl][8 chunk][2][256]
#define OF_TAB   (OF_P2 + 49152)           // 6 tables f32 [257][256]: Aq Bq Ak Bk Av Bv
#define OF_WP    (OF_TAB + 789504)         // Wp' bf16 frag-major (524288 u16)
#define OF_ORAW  (OF_WP + 524288)          // o_raw bf16 frag-major [256 kb8][25600 m][8]
#define OF_WQB   OF_ORAW                   // overlay: Wq'/Wk'/Wv' bf16 row-major (3x65536),
                                           // dead before fused writes o_raw
#define NPM8     204800                    // 25600 patches * 8

static __device__ __forceinline__ float bf2f(u16 u) {
  union { unsigned int i; float f; } z; z.i = ((unsigned int)u) << 16; return z.f;
}
static __device__ __forceinline__ u16 f2bf(float f) {
  union { float f; unsigned int i; } z; z.f = f;
  unsigned int x = z.i + 0x7fffu + ((z.i >> 16) & 1u);  // RNE
  return (u16)(x >> 16);
}
static __device__ __forceinline__ unsigned pkbf(float lo, float hi) {
  __hip_bfloat162 h = __float22bfloat162_rn(make_float2(lo, hi));  // v_cvt_pk_bf16_f32
  unsigned r; __builtin_memcpy(&r, &h, 4); return r;
}

// bf16 (0) vs f32 (1) input detection on first 256 u16 of spec; per-wave ballot.
static __device__ __forceinline__ int detect_flag(const u16* __restrict__ sp) {
  const int lane = threadIdx.x & 63;
  int bad = 0;
#pragma unroll
  for (int j = 0; j < 4; ++j) {
    u16 v = sp[lane * 4 + j];
    int e = (v >> 7) & 0xFF;
    bad += (e >= 137);
  }
  return (__popcll(__ballot(bad > 0)) >= 4) ? 1 : 0;
}

#define CV(src, idx) (flag ? f2bf(((const float*)(src))[idx]) : ((const u16*)(src))[idx])

// prep1: blocks 0..175: 11 fold GEMMs of 256x256x256 (16 sub-blocks of 64x64),
// B-tile staged through LDS (coalesced b128, pad 72 u16 / row):
//   g=0..2:  Wg' = W2 @ {Wq,Wk,Wv} -> bf16 row-major [k][n] at OF_WQB
//   g=3..10: Wp'_p = Wo @ Wp[p*256:...] -> bf16 frag-major at OF_WP
// blocks 176..186: fq/fk/fv (f32) + 8 f32 partials for fused bp.
// block  187: threshold sort + event/base coef tables (for the prefix scan).
__global__ void prep1_kernel(
    const void* spec, const void* W1, const void* b1, const void* W2,
    const void* Wq, const void* bq, const void* Wk, const void* bk, const void* Wv,
    const void* bv_, const void* Wo, const void* bo, const void* Wp, const void* b2,
    u16* __restrict__ ws) {
  const int flag = detect_flag((const u16*)spec);
  const int b = blockIdx.x, tid = threadIdx.x;
  __shared__ u16 Bs[32 * 72];
  if (b == 187) {
    // sort thresholds t_k = -b1_k/W1_k; emit event order + coefs.
    __shared__ float st[256];
    __shared__ int   sk[256];
    __shared__ float w1s[256], b1s[256];
    w1s[tid] = flag ? ((const float*)W1)[tid] : bf2f(((const u16*)W1)[tid]);
    b1s[tid] = flag ? ((const float*)b1)[tid] : bf2f(((const u16*)b1)[tid]);
    __syncthreads();
    {
      const float w = w1s[tid];
      st[tid] = (w != 0.f) ? (-b1s[tid] / w) : 1e30f;
      sk[tid] = tid;
    }
    for (int size = 2; size <= 256; size <<= 1) {
      for (int stride = size >> 1; stride > 0; stride >>= 1) {
        __syncthreads();
        const int ixj = tid ^ stride;
        if (ixj > tid) {
          const bool up = ((tid & size) == 0);
          float a = st[tid], bq2 = st[ixj];
          if (up ? (a > bq2) : (a < bq2)) {
            int ka = sk[tid];
            st[tid] = bq2; st[ixj] = a;
            sk[tid] = sk[ixj]; sk[ixj] = ka;
          }
        }
      }
    }
    __syncthreads();
    ((float*)(ws + OF_SORT))[tid] = st[tid];
    ws[OF_EVK + tid] = (u16)sk[tid];
    {
      const int ke = sk[tid];
      const float w = w1s[ke], bb = b1s[ke];
      const float sg = (w > 0.f) ? 1.f : ((w < 0.f) ? -1.f : 0.f);
      ((float*)(ws + OF_CA))[tid] = sg * w;
      ((float*)(ws + OF_CB))[tid] = sg * bb;
    }
    {
      const float wk = w1s[tid], bk2 = b1s[tid];
      const bool act0 = (wk < 0.f) || (wk == 0.f && bk2 > 0.f);
      ((float*)(ws + OF_MA))[tid] = act0 ? wk : 0.f;
      ((float*)(ws + OF_MB))[tid] = act0 ? bk2 : 0.f;
    }
    return;
  }
  if (b >= 176) {
    const int t = b - 176, n = tid;
    if (t < 3) {
      const void* SB = (t == 0) ? Wq : (t == 1) ? Wk : Wv;
      const void* bs = (t == 0) ? bq : (t == 1) ? bk : bv_;
      float acc;
      if (flag) {
        acc = ((const float*)bs)[n];
        const float* Bf = (const float*)SB; const float* b2f = (const float*)b2;
        for (int k = 0; k < 256; ++k) acc = fmaf(b2f[k], Bf[k * 256 + n], acc);
      } else {
        acc = bf2f(((const u16*)bs)[n]);
        const u16* Bh = (const u16*)SB; const u16* b2h = (const u16*)b2;
        for (int k = 0; k < 256; ++k) acc = fmaf(bf2f(b2h[k]), bf2f(Bh[k * 256 + n]), acc);
      }
      ((float*)(ws + OF_FQKV))[t * 256 + n] = acc;
    } else {
      const int p = t - 3;
      float acc = 0.f;
      if (flag) {
        const float* Wf = (const float*)Wp; const float* bf = (const float*)bo;
        for (int m = 0; m < 256; ++m) acc = fmaf(bf[m], Wf[(p * 256 + m) * 256 + n], acc);
      } else {
        const u16* Wh = (const u16*)Wp; const u16* bh = (const u16*)bo;
        for (int m = 0; m < 256; ++m)
          acc = fmaf(bf2f(bh[m]), bf2f(Wh[(p * 256 + m) * 256 + n]), acc);
      }
      ((float*)(ws + OF_PART))[p * 256 + n] = acc;
    }
    return;
  }
  // fold GEMMs
  const int g = b >> 4, sub = b & 15;
  const int r0 = (sub >> 2) * 64, c0 = (sub & 3) * 64;
  const void* SA = (g < 3) ? W2 : Wo;
  const void* SB = (g == 0) ? Wq : (g == 1) ? Wk : (g == 2) ? Wv : Wp;
  const int brow0 = (g < 3) ? 0 : (g - 3) * 256;
  const int w = tid >> 6, lane = tid & 63, l15 = lane & 15, quad = lane >> 4;
  const int arow = r0 + w * 16 + l15;
  const int srow = tid >> 3, sseg = tid & 7;   // staging: row 0..31, 8-col segment
  floatx4 acc[4];
#pragma unroll
  for (int ni = 0; ni < 4; ++ni) acc[ni] = (floatx4){0.f, 0.f, 0.f, 0.f};
  for (int kc = 0; kc < 8; ++kc) {
    __syncthreads();
    if (flag) {
      const float* Bf = (const float*)SB;
      const float* src = Bf + (brow0 + kc * 32 + srow) * 256 + c0 + sseg * 8;
      floatx4 f0 = *(const floatx4*)src, f1 = *(const floatx4*)(src + 4);
      union { short8 s8; unsigned u[4]; } t;
      t.u[0] = pkbf(f0[0], f0[1]); t.u[1] = pkbf(f0[2], f0[3]);
      t.u[2] = pkbf(f1[0], f1[1]); t.u[3] = pkbf(f1[2], f1[3]);
      *(short8*)(Bs + srow * 72 + sseg * 8) = t.s8;
    } else {
      const u16* Bh = (const u16*)SB;
      *(short8*)(Bs + srow * 72 + sseg * 8) =
          *(const short8*)(Bh + (brow0 + kc * 32 + srow) * 256 + c0 + sseg * 8);
    }
    __syncthreads();
    const int k0 = kc * 32 + quad * 8;
    union { short8 s8; u16 u[8]; } av;
    if (flag) {
      const float* A = (const float*)SA;
      floatx4 a0 = *(const floatx4*)(A + arow * 256 + k0);
      floatx4 a1 = *(const floatx4*)(A + arow * 256 + k0 + 4);
      av.u[0] = f2bf(a0[0]); av.u[1] = f2bf(a0[1]); av.u[2] = f2bf(a0[2]); av.u[3] = f2bf(a0[3]);
      av.u[4] = f2bf(a1[0]); av.u[5] = f2bf(a1[1]); av.u[6] = f2bf(a1[2]); av.u[7] = f2bf(a1[3]);
    } else {
      const u16* A = (const u16*)SA;
      av.s8 = *(const short8*)(A + arow * 256 + k0);
    }
#pragma unroll
    for (int ni = 0; ni < 4; ++ni) {
      union { short8 s8; u16 u[8]; } bu;
#pragma unroll
      for (int j = 0; j < 8; ++j) bu.u[j] = Bs[(quad * 8 + j) * 72 + ni * 16 + l15];
      acc[ni] = MFMA16(av.s8, bu.s8, acc[ni]);
    }
  }
  if (g < 3) {
    u16* dst = ws + OF_WQB + g * 65536;
#pragma unroll
    for (int ni = 0; ni < 4; ++ni) {
      const int n = c0 + ni * 16 + l15;
#pragma unroll
      for (int r = 0; r < 4; ++r) {
        const int k = r0 + w * 16 + quad * 4 + r;
        dst[k * 256 + n] = f2bf(acc[ni][r]);
      }
    }
  } else {
    u16* dst = ws + OF_WP;
#pragma unroll
    for (int ni = 0; ni < 4; ++ni) {
      const int n = c0 + ni * 16 + l15;
#pragma unroll
      for (int r = 0; r < 4; ++r) {
        const int k = brow0 + r0 + w * 16 + quad * 4 + r;
        dst[(k >> 3) * 2048 + n * 8 + (k & 7)] = f2bf(acc[ni][r]);
      }
    }
  }
}

// prep2a: scan partials. 48 blocks = 6 tables x 8 chunks; each block sums its
// 32 base terms and 32 event terms per column (independent coalesced loads).
__global__ void prep2a_kernel(u16* __restrict__ ws) {
  const int tbl = blockIdx.x >> 3, chunk = blockIdx.x & 7;
  const int n = threadIdx.x;
  const int m = tbl >> 1, isB = tbl & 1;
  const u16* S = ws + OF_WQB + m * 65536;
  const float* MC = (const float*)(ws + (isB ? OF_MB : OF_MA));
  const float* CC = (const float*)(ws + (isB ? OF_CB : OF_CA));
  const u16* EVK = ws + OF_EVK;
  float bacc = 0.f, eacc = 0.f;
#pragma unroll 8
  for (int j = 0; j < 32; ++j) {
    const int k = chunk * 32 + j;
    bacc = fmaf(MC[k], bf2f(S[k * 256 + n]), bacc);
    eacc = fmaf(CC[k], bf2f(S[EVK[k] * 256 + n]), eacc);
  }
  float* P = (float*)(ws + OF_P2);
  P[((tbl * 8 + chunk) * 2 + 0) * 256 + n] = bacc;
  P[((tbl * 8 + chunk) * 2 + 1) * 256 + n] = eacc;
}

// prep2b: 48 blocks = 6 tables x 8 segments. Seed cur from base partials +
// event-chunk prefix, then a 31/32-step local walk writing rows rlo..rlo+31
// (seg 7 also writes row 256). Tables stored f32.
__global__ void prep2b_kernel(u16* __restrict__ ws) {
  const int tbl = blockIdx.x >> 3, seg = blockIdx.x & 7;
  const int n = threadIdx.x;
  const int m = tbl >> 1, isB = tbl & 1;
  const u16* S = ws + OF_WQB + m * 65536;
  const float* CC = (const float*)(ws + (isB ? OF_CB : OF_CA));
  const u16* EVK = ws + OF_EVK;
  const float* P = (const float*)(ws + OF_P2);
  float cur = isB ? ((const float*)(ws + OF_FQKV))[m * 256 + n] : 0.f;
#pragma unroll
  for (int c = 0; c < 8; ++c) cur += P[((tbl * 8 + c) * 2 + 0) * 256 + n];
  for (int c = 0; c < seg; ++c) cur += P[((tbl * 8 + c) * 2 + 1) * 256 + n];
  float* dst = (float*)(ws + OF_TAB) + tbl * 65792;
  const int rlo = seg * 32;
  dst[rlo * 256 + n] = cur;
  const int nev = (seg == 7) ? 32 : 31;
  for (int i = 0; i < nev; ++i) {
    const int e = rlo + i;
    cur = fmaf(CC[e], bf2f(S[EVK[e] * 256 + n]), cur);
    dst[(e + 1) * 256 + n] = cur;
  }
}

// One block = 64 tokens = 8 windows. q/k/v from f32 threshold-rank tables,
// packed to bf16 via v_cvt_pk_bf16_f32. Swapped QK^T (MFMA(K,Q)) makes the
// softmax row lane-local: 2 shfl/head. Raw o written frag-major to o_raw.
__global__ __launch_bounds__(256) void fused_lite_kernel(
    const void* __restrict__ spec, const float* __restrict__ tsort,
    const float* __restrict__ tAq, const float* __restrict__ tBq,
    const float* __restrict__ tAk, const float* __restrict__ tBk,
    const float* __restrict__ tAv, const float* __restrict__ tBv,
    u16* __restrict__ oraw)
{
  __shared__ u16 vbT[16384];          // 64 tok x 256 dims transposed, swizzled (32 KB)
  __shared__ u16 pscr[1024];          // per-wave P scratch (head-at-a-time)
  __shared__ float sS[64];
  __shared__ int   sR[64];
  __shared__ int   part[256];

  const int flag = detect_flag((const u16*)spec);
  const int tid = threadIdx.x;
  const int wave = tid >> 6, lane = tid & 63;
  const int l15 = lane & 15, quad = lane >> 4;
  const int tile0 = blockIdx.x * 64;
  const floatx4 zero4 = (floatx4){0.f, 0.f, 0.f, 0.f};

  // phase 0: per-token s and rank r = #{t < s} (4 threads/token count 64 each)
  {
    const int m = tid & 63, qt = tid >> 6;
    const float sm = flag ? ((const float*)spec)[tile0 + m]
                          : bf2f(((const u16*)spec)[tile0 + m]);
    int cnt = 0;
#pragma unroll 8
    for (int j = 0; j < 64; ++j) cnt += (tsort[qt * 64 + j] < sm) ? 1 : 0;
    part[tid] = cnt;
    __syncthreads();
    if (tid < 64) {
      sR[tid] = part[tid] + part[tid + 64] + part[tid + 128] + part[tid + 192];
      sS[tid] = sm;
    }
    __syncthreads();
  }

  // phase 1: v-fill, token-pairs. Thread (tp, db) handles tokens {2tp,2tp+1},
  // dims db*32..+32; packed b32 stores, conflict-free swizzle.
  {
    const int tp = tid & 31, db = tid >> 5;
    const int t0 = tp * 2, t1 = t0 + 1;
    const float s0 = sS[t0], s1 = sS[t1];
    const float* A0 = tAv + sR[t0] * 256;
    const float* B0 = tBv + sR[t0] * 256;
    const float* A1 = tAv + sR[t1] * 256;
    const float* B1 = tBv + sR[t1] * 256;
    unsigned* vbT32 = (unsigned*)vbT;
#pragma unroll
    for (int j = 0; j < 32; j += 4) {
      const int d = db * 32 + j;
      floatx4 a0 = *(const floatx4*)(A0 + d), b0 = *(const floatx4*)(B0 + d);
      floatx4 a1 = *(const floatx4*)(A1 + d), b1 = *(const floatx4*)(B1 + d);
#pragma unroll
      for (int e = 0; e < 4; ++e) {
        const int dd = d + e;
        vbT32[dd * 32 + ((((tp >> 2) ^ (dd & 7)) << 2) | (tp & 3))] =
            pkbf(fmaf(s0, a0[e], b0[e]), fmaf(s1, a1[e], b1[e]));
      }
    }
  }
  __syncthreads();

  // phase 2: attention, head-at-a-time. Wave w owns windows {2w, 2w+1}.
  unsigned opk[32];
  {
    const int w2 = wave * 2;
    const int tok = wave * 16 + l15;
    const int r_t = sR[tok];
    const float s_t = sS[tok];
    const int valid = ((l15 >> 3) == (quad >> 1));
    u16* ps = pscr + wave * 256;
    const float* Aq = tAq + r_t * 256;
    const float* Bq = tBq + r_t * 256;
    const float* Ak = tAk + r_t * 256;
    const float* Bk = tBk + r_t * 256;
#pragma unroll
    for (int h = 0; h < 8; ++h) {
      const int d8 = h * 32 + quad * 8;
      short8 qv, kv;
      {
        floatx4 a0 = *(const floatx4*)(Aq + d8), a1 = *(const floatx4*)(Aq + d8 + 4);
        floatx4 b0 = *(const floatx4*)(Bq + d8), b1 = *(const floatx4*)(Bq + d8 + 4);
        union { short8 s8; unsigned u[4]; } z;
        z.u[0] = pkbf(fmaf(s_t, a0[0], b0[0]), fmaf(s_t, a0[1], b0[1]));
        z.u[1] = pkbf(fmaf(s_t, a0[2], b0[2]), fmaf(s_t, a0[3], b0[3]));
        z.u[2] = pkbf(fmaf(s_t, a1[0], b1[0]), fmaf(s_t, a1[1], b1[1]));
        z.u[3] = pkbf(fmaf(s_t, a1[2], b1[2]), fmaf(s_t, a1[3], b1[3]));
        qv = z.s8;
      }
      {
        floatx4 a0 = *(const floatx4*)(Ak + d8), a1 = *(const floatx4*)(Ak + d8 + 4);
        floatx4 b0 = *(const floatx4*)(Bk + d8), b1 = *(const floatx4*)(Bk + d8 + 4);
        union { short8 s8; unsigned u[4]; } z;
        z.u[0] = pkbf(fmaf(s_t, a0[0], b0[0]), fmaf(s_t, a0[1], b0[1]));
        z.u[1] = pkbf(fmaf(s_t, a0[2], b0[2]), fmaf(s_t, a0[3], b0[3]));
        z.u[2] = pkbf(fmaf(s_t, a1[0], b1[0]), fmaf(s_t, a1[1], b1[1]));
        z.u[3] = pkbf(fmaf(s_t, a1[2], b1[2]), fmaf(s_t, a1[3], b1[3]));
        kv = z.s8;
      }
      // swapped: sc[r] = score[k = quad*4+r][q = l15]
      floatx4 sc = MFMA16(kv, qv, zero4);
      const float SC = 0.17677669529663687f;   // 1/sqrt(32)
      float s0 = sc[0] * SC, s1 = sc[1] * SC, s2 = sc[2] * SC, s3 = sc[3] * SC;
      float m4 = fmaxf(fmaxf(s0, s1), fmaxf(s2, s3));
      float mx = fmaxf(m4, __shfl_xor(m4, 16));
      float p0 = __expf(s0 - mx), p1 = __expf(s1 - mx);
      float p2 = __expf(s2 - mx), p3 = __expf(s3 - mx);
      float sm = (p0 + p1) + (p2 + p3);
      float su = sm + __shfl_xor(sm, 16);
      float inv = 1.f / su;
      float v0 = valid ? p0 * inv : 0.f, v1 = valid ? p1 * inv : 0.f;
      float v2 = valid ? p2 * inv : 0.f, v3 = valid ? p3 * inv : 0.f;
      union { short4_t s4; unsigned u[2]; } pw;
      pw.u[0] = pkbf(v0, v1); pw.u[1] = pkbf(v2, v3);
      *(short4_t*)(ps + l15 * 16 + quad * 4) = pw.s4;   // [q=l15][k=quad*4..+3]
#pragma unroll
      for (int dh = 0; dh < 2; ++dh) {
        const int vcol = h * 32 + dh * 16 + l15;
        short8 pa = (short8){0, 0, 0, 0, 0, 0, 0, 0};
        short8 vf = (short8){0, 0, 0, 0, 0, 0, 0, 0};
        if (quad < 2) {
          pa = *(const short8*)(ps + l15 * 16 + quad * 8);
          vf = *(const short8*)(vbT + vcol * 64 + (((w2 + quad) ^ (vcol & 7)) << 3));
        }
        floatx4 o = MFMA16(pa, vf, zero4);
        opk[(h * 2 + dh) * 2]     = pkbf(o[0], o[1]);
        opk[(h * 2 + dh) * 2 + 1] = pkbf(o[2], o[3]);
      }
    }
  }

  // phase 3: opk -> o_raw (global, fragment-major).
  // token row = quad*4+r -> win = 2*wave + (quad>>1), p = (quad&1)*4 + r;
  // D = h*32 + dh*16 + l15 -> e8 = h*4 + dh*2 + (l15>>3).
  {
    const int mbase = (blockIdx.x * 8 + wave * 2 + (quad >> 1)) * 8 + (l15 & 7);
    const int pb4 = (quad & 1) * 4;
#pragma unroll
    for (int h = 0; h < 8; ++h)
#pragma unroll
      for (int dh = 0; dh < 2; ++dh) {
        const int oi = (h * 2 + dh) * 2;
        const int e8 = h * 4 + dh * 2 + (l15 >> 3);
        const unsigned lo = opk[oi], hi = opk[oi + 1];
        oraw[((pb4 + 0) * 32 + e8) * NPM8 + mbase] = (u16)lo;
        oraw[((pb4 + 1) * 32 + e8) * NPM8 + mbase] = (u16)(lo >> 16);
        oraw[((pb4 + 2) * 32 + e8) * NPM8 + mbase] = (u16)hi;
        oraw[((pb4 + 3) * 32 + e8) * NPM8 + mbase] = (u16)(hi >> 16);
      }
  }
}

// Patch projection GEMM: [25600 x 2048] @ Wp' [2048 x 256] + fb.
// M-tile 64, N-tile 128, 4 waves each 64x32; A and B direct from global
// (both fragment-major, coalesced b128); no LDS.
__global__ __launch_bounds__(256) void patch_gemm_kernel(
    const u16* __restrict__ spec_raw,
    const u16* __restrict__ oraw, const u16* __restrict__ sWp,
    const void* __restrict__ bp, const float* __restrict__ part,
    void* __restrict__ out)
{
  const int flag = detect_flag(spec_raw);
  const int tid = threadIdx.x;
  const int wave = tid >> 6, lane = tid & 63;
  const int l15 = lane & 15, quad = lane >> 4;
  const int m0 = (blockIdx.x >> 1) * 64;
  const int n0 = (blockIdx.x & 1) * 128 + wave * 32;
  const floatx4 zero4 = (floatx4){0.f, 0.f, 0.f, 0.f};

  floatx4 acc[4][2];
#pragma unroll
  for (int mi = 0; mi < 4; ++mi)
#pragma unroll
    for (int ni = 0; ni < 2; ++ni) acc[mi][ni] = zero4;

  const u16* ap = oraw + quad * NPM8 + (m0 + l15) * 8;
  const u16* bpw = sWp + quad * 2048 + (n0 + l15) * 8;
#pragma unroll 4
  for (int kk = 0; kk < 64; ++kk) {
    short8 b0 = *(const short8*)(bpw);
    short8 b1 = *(const short8*)(bpw + 128);         // +16 cols
#pragma unroll
    for (int mi = 0; mi < 4; ++mi) {
      short8 a = *(const short8*)(ap + mi * 128);    // +16 rows per mi
      acc[mi][0] = MFMA16(a, b0, acc[mi][0]);
      acc[mi][1] = MFMA16(a, b1, acc[mi][1]);
    }
    ap += 4 * NPM8;
    bpw += 4 * 2048;
  }

  // epilogue: fb = bp + sum of the 8 bo@Wp_p partials (f32)
#pragma unroll
  for (int ni = 0; ni < 2; ++ni) {
    const int n = n0 + ni * 16 + l15;
    float bb = bf2f(CV(bp, n));
#pragma unroll
    for (int p = 0; p < 8; ++p) bb += part[p * 256 + n];
#pragma unroll
    for (int mi = 0; mi < 4; ++mi) {
      const int mr = m0 + mi * 16 + quad * 4;
      if (flag) {
        float* po = (float*)out;
#pragma unroll
        for (int r = 0; r < 4; ++r)
          po[(mr + r) * 256 + n] = acc[mi][ni][r] + bb;
      } else {
        u16* po = (u16*)out;
#pragma unroll
        for (int r = 0; r < 4; ++r)
          po[(mr + r) * 256 + n] = f2bf(acc[mi][ni][r] + bb);
      }
    }
  }
}

extern "C" void kernel_launch(void* const* d_in, const int* in_sizes, int n_in,
                              void* d_out, int out_size, void* d_ws, size_t ws_size,
                              hipStream_t stream) {
  (void)in_sizes; (void)n_in; (void)out_size; (void)ws_size;
  u16* ws = (u16*)d_ws;

  prep1_kernel<<<188, 256, 0, stream>>>(
      d_in[0], d_in[1], d_in[2], d_in[3],
      d_in[5], d_in[6], d_in[7], d_in[8], d_in[9], d_in[10],
      d_in[11], d_in[12], d_in[13], d_in[4], ws);
  prep2a_kernel<<<48, 256, 0, stream>>>(ws);
  prep2b_kernel<<<48, 256, 0, stream>>>(ws);
  const float* TB = (const float*)(ws + OF_TAB);
  fused_lite_kernel<<<3200, 256, 0, stream>>>(
      d_in[0], (const float*)(ws + OF_SORT),
      TB,             TB + 65792,
      TB + 2 * 65792, TB + 3 * 65792,
      TB + 4 * 65792, TB + 5 * 65792,
      ws + OF_ORAW);
  patch_gemm_kernel<<<800, 256, 0, stream>>>(
      (const u16*)d_in[0],
      ws + OF_ORAW, ws + OF_WP,
      d_in[14], (const float*)(ws + OF_PART),
      d_out);
}